// Round 3
// baseline (70.033 us; speedup 1.0000x reference)
//
#include <hip/hip_runtime.h>
#include <hip/hip_bf16.h>

typedef __attribute__((ext_vector_type(4))) float f32x4;
typedef __attribute__((ext_vector_type(8))) short bf16x8;

#define MFMA16(a, b, c) __builtin_amdgcn_mfma_f32_16x16x32_bf16(a, b, c, 0, 0, 0)

constexpr int Bc = 8, Hc = 8;
constexpr int NQ = 1024;      // query rows per (b,h)
constexpr int NK = 1024;      // key rows per (b,h)
constexpr int RS = 512;       // H*E floats: row stride in the f32 tensors
constexpr int Ec = 64;        // head dim
constexpr int KT = 64;        // keys per tile
constexpr int QT = 64;        // q rows per block (4 waves x 16)
constexpr int NT = NK / KT;   // 16 tiles
constexpr float QSCALE = 0.125f;  // 1/sqrt(64), exact pow2, folded into Q

__device__ __forceinline__ short f2bf(float x) {
    return (short)__builtin_bit_cast(unsigned short, __float2bfloat16(x));
}

__device__ __forceinline__ bf16x8 pack2(float4 a, float4 b) {
    bf16x8 r;
    r[0] = f2bf(a.x); r[1] = f2bf(a.y); r[2] = f2bf(a.z); r[3] = f2bf(a.w);
    r[4] = f2bf(b.x); r[5] = f2bf(b.y); r[6] = f2bf(b.z); r[7] = f2bf(b.w);
    return r;
}

__device__ __forceinline__ bf16x8 pack2s(float4 a, float4 b, float s) {
    bf16x8 r;
    r[0] = f2bf(a.x * s); r[1] = f2bf(a.y * s); r[2] = f2bf(a.z * s); r[3] = f2bf(a.w * s);
    r[4] = f2bf(b.x * s); r[5] = f2bf(b.y * s); r[6] = f2bf(b.z * s); r[7] = f2bf(b.w * s);
    return r;
}

__device__ __forceinline__ void gload16(const short* src, short* dst) {
    // direct global->LDS DMA, 16B per lane; LDS dest = uniform base + lane*16
    __builtin_amdgcn_global_load_lds((const __attribute__((address_space(1))) void*)src,
                                     (__attribute__((address_space(3))) void*)dst, 16, 0, 0);
}

// ---------------- pass 1: K/V fp32 -> bf16, V transposed ----------------
// Kbf: [head(64)][key(1024)][e(64)]   Vt: [head(64)][e(64)][key(1024)]
__global__ __launch_bounds__(256, 4)
void cvt_kv(const float* __restrict__ Kg, const float* __restrict__ Vg,
            short* __restrict__ Kbf, short* __restrict__ Vt) {
    __shared__ __attribute__((aligned(16))) short Vl[64][72];  // [e][key], 144B stride (16B-aligned rows)
    const int tid  = threadIdx.x;
    const int head = blockIdx.x >> 4;   // b*8+h
    const int kb   = blockIdx.x & 15;   // key block of 64
    const int b    = head >> 3, h = head & 7;
    const int row  = tid >> 2, q = tid & 3;   // key row 0..63, e-quarter 0..3

    const size_t gin = (((size_t)(b * NK + kb * 64 + row)) * 8 + h) * 64 + q * 16;
    const float4* kp = (const float4*)(Kg + gin);
    float4 k0 = kp[0], k1 = kp[1], k2 = kp[2], k3 = kp[3];
    short* kout = Kbf + ((size_t)head * NK + kb * 64 + row) * 64 + q * 16;
    ((bf16x8*)kout)[0] = pack2(k0, k1);
    ((bf16x8*)kout)[1] = pack2(k2, k3);

    const float4* vp = (const float4*)(Vg + gin);
    float4 v0 = vp[0], v1 = vp[1], v2 = vp[2], v3 = vp[3];
    const float vv[16] = {v0.x, v0.y, v0.z, v0.w, v1.x, v1.y, v1.z, v1.w,
                          v2.x, v2.y, v2.z, v2.w, v3.x, v3.y, v3.z, v3.w};
#pragma unroll
    for (int j = 0; j < 16; ++j) Vl[q * 16 + j][row] = f2bf(vv[j]);
    __syncthreads();
    // row now plays the role of e; write coalesced bf16 rows of Vt
    short* vout = Vt + ((size_t)head * Ec + row) * NK + kb * 64 + q * 16;
    ((bf16x8*)vout)[0] = *(const bf16x8*)&Vl[row][q * 16];
    ((bf16x8*)vout)[1] = *(const bf16x8*)&Vl[row][q * 16 + 8];
}

// ---------------- pass 2: flash attention, all-bf16 staging ----------------
// LDS tiles 64x64 bf16 (128B rows), element-chunk (row, j) at byte
// row*128 + ((j*16) ^ ((row&7)<<4)). gload_lds writes linearly, so the
// per-lane GLOBAL source is pre-swizzled: j_src = (lane&7) ^ (row&7).
__global__ __launch_bounds__(256, 4)
void fully_attn_kernel(const float* __restrict__ Qg, const short* __restrict__ Kbf,
                       const short* __restrict__ Vt, float* __restrict__ Og) {
    __shared__ __attribute__((aligned(16))) short Kl[2][64][64];  // [key][e]
    __shared__ __attribute__((aligned(16))) short Vl[2][64][64];  // [e][key]
    __shared__ __attribute__((aligned(16))) short Pl[4][16][64];  // per-wave [q][key]

    const int tid  = threadIdx.x;
    const int lane = tid & 63;
    const int wv   = tid >> 6;
    const int c    = lane & 15;
    const int g    = lane >> 4;
    const int swzc = (c & 7) << 4;

    // XCD-aware remap: one head's 16 q-blocks share an XCD (L2 holds its 256KB K/V)
    const int bid  = blockIdx.x;
    const int head = (bid & 7) * 8 + (bid >> 7);
    const int qb   = (bid >> 3) & 15;
    const int b    = head >> 3, h = head & 7;

    const size_t headQ = (size_t)b * NQ * RS + (size_t)h * Ec;
    const short* KbfH = Kbf + (size_t)head * NK * Ec;
    const short* VtH  = Vt + (size_t)head * Ec * NK;

    // ---- Q fragments, scale folded ----
    const int qrow = qb * QT + wv * 16 + c;
    const float4* qp4 = (const float4*)(Qg + headQ + (size_t)qrow * RS + g * 8);
    const bf16x8 aq0 = pack2s(qp4[0], qp4[1], QSCALE);
    const bf16x8 aq1 = pack2s(qp4[8], qp4[9], QSCALE);

    // staging geometry: wave wv stages rows wv*16 .. wv*16+15 of both tiles
    const int srow0 = wv * 16 + (lane >> 3);
    const int srow1 = srow0 + 8;
    const int jj = (lane & 7) ^ ((lane >> 3) & 7);  // inverse-swizzled source chunk

#define STAGE(bufi, tt)                                                        \
    {                                                                          \
        gload16(KbfH + ((size_t)(tt) * KT + srow0) * 64 + jj * 8,              \
                &Kl[bufi][wv * 16][0]);                                        \
        gload16(KbfH + ((size_t)(tt) * KT + srow1) * 64 + jj * 8,              \
                &Kl[bufi][wv * 16 + 8][0]);                                    \
        gload16(VtH + (size_t)srow0 * NK + (tt) * KT + jj * 8,                 \
                &Vl[bufi][wv * 16][0]);                                        \
        gload16(VtH + (size_t)srow1 * NK + (tt) * KT + jj * 8,                 \
                &Vl[bufi][wv * 16 + 8][0]);                                    \
    }

    // prologue
    STAGE(0, 0);
    __syncthreads();  // drains vmcnt

    float m_r[4], l_r[4];
    f32x4 o[4];
#pragma unroll
    for (int r = 0; r < 4; ++r) { m_r[r] = -1e30f; l_r[r] = 0.0f; }
#pragma unroll
    for (int n = 0; n < 4; ++n) o[n] = (f32x4)(0.0f);

    int cur = 0;
    for (int t = 0; t < NT; ++t) {
        if (t + 1 < NT) STAGE(cur ^ 1, t + 1);  // loads fly under compute

        // ---- S = Q K^T ----
        f32x4 cs[4];
        __builtin_amdgcn_s_setprio(1);
#pragma unroll
        for (int n = 0; n < 4; ++n) {
            const char* kr = (const char*)&Kl[cur][n * 16 + c][0];
            bf16x8 bk0 = *(const bf16x8*)(kr + ((g * 16) ^ swzc));
            bf16x8 bk1 = *(const bf16x8*)(kr + ((64 + g * 16) ^ swzc));
            f32x4 acc = (f32x4)(0.0f);
            acc = MFMA16(aq0, bk0, acc);
            acc = MFMA16(aq1, bk1, acc);
            cs[n] = acc;
        }
        __builtin_amdgcn_s_setprio(0);

        // ---- online softmax (lane holds q-rows g*4+r, key n*16+c) ----
#pragma unroll
        for (int r = 0; r < 4; ++r) {
            float v = fmaxf(fmaxf(cs[0][r], cs[1][r]), fmaxf(cs[2][r], cs[3][r]));
            v = fmaxf(v, __shfl_xor(v, 1));
            v = fmaxf(v, __shfl_xor(v, 2));
            v = fmaxf(v, __shfl_xor(v, 4));
            v = fmaxf(v, __shfl_xor(v, 8));
            float mn = fmaxf(m_r[r], v);
            float alpha = __expf(m_r[r] - mn);
            float rsum = 0.0f;
#pragma unroll
            for (int n = 0; n < 4; ++n) {
                float p = __expf(cs[n][r] - mn);
                cs[n][r] = p;
                rsum += p;
            }
            rsum += __shfl_xor(rsum, 1);
            rsum += __shfl_xor(rsum, 2);
            rsum += __shfl_xor(rsum, 4);
            rsum += __shfl_xor(rsum, 8);
            l_r[r] = l_r[r] * alpha + rsum;
            m_r[r] = mn;
#pragma unroll
            for (int n = 0; n < 4; ++n) o[n][r] *= alpha;
        }

        // ---- P: C-layout -> A-layout via per-wave swizzled LDS round-trip ----
#pragma unroll
        for (int n = 0; n < 4; ++n)
#pragma unroll
            for (int r = 0; r < 4; ++r) {
                const int row = g * 4 + r;
                *(short*)((char*)&Pl[wv][row][0] +
                          ((n * 32 + c * 2) ^ ((row & 7) << 4))) = f2bf(cs[n][r]);
            }
        const char* pr = (const char*)&Pl[wv][c][0];
        bf16x8 pa0 = *(const bf16x8*)(pr + ((g * 16) ^ swzc));
        bf16x8 pa1 = *(const bf16x8*)(pr + ((64 + g * 16) ^ swzc));

        // ---- O += P V ----
        __builtin_amdgcn_s_setprio(1);
#pragma unroll
        for (int n = 0; n < 4; ++n) {
            const char* vr = (const char*)&Vl[cur][n * 16 + c][0];
            bf16x8 bv0 = *(const bf16x8*)(vr + ((g * 16) ^ swzc));
            bf16x8 bv1 = *(const bf16x8*)(vr + ((64 + g * 16) ^ swzc));
            o[n] = MFMA16(pa0, bv0, o[n]);
            o[n] = MFMA16(pa1, bv1, o[n]);
        }
        __builtin_amdgcn_s_setprio(0);

        __syncthreads();  // compiler drains vmcnt(0) here: prefetch landed
        cur ^= 1;
    }

    // ---- epilogue ----
    const size_t obase = headQ + (size_t)(qb * QT + wv * 16) * RS;
#pragma unroll
    for (int n = 0; n < 4; ++n)
#pragma unroll
        for (int r = 0; r < 4; ++r) {
            const int row = g * 4 + r;
            Og[obase + (size_t)row * RS + n * 16 + c] = o[n][r] / l_r[r];
        }
}

extern "C" void kernel_launch(void* const* d_in, const int* in_sizes, int n_in,
                              void* d_out, int out_size, void* d_ws, size_t ws_size,
                              hipStream_t stream) {
    const float* Qg = (const float*)d_in[0];
    const float* Kg = (const float*)d_in[1];
    const float* Vg = (const float*)d_in[2];
    float* Og = (float*)d_out;

    short* Kbf = (short*)d_ws;                                  // 8.39 MB
    short* Vt  = (short*)d_ws + (size_t)64 * NK * Ec;           // 8.39 MB
    // total ws use: 16.78 MB

    hipLaunchKernelGGL(cvt_kv, dim3(64 * 16), dim3(256), 0, stream, Kg, Vg, Kbf, Vt);
    hipLaunchKernelGGL(fully_attn_kernel, dim3(Bc * Hc * (NQ / QT)), dim3(256), 0, stream,
                       Qg, Kbf, Vt, Og);
}

// Round 4
// 47.041 us; speedup vs baseline: 1.4888x; 1.4888x over previous
//
#include <hip/hip_runtime.h>
#include <hip/hip_bf16.h>

typedef __attribute__((ext_vector_type(4))) float f32x4;
typedef __attribute__((ext_vector_type(16))) float f32x16;
typedef __attribute__((ext_vector_type(8))) short bf16x8;
typedef __attribute__((ext_vector_type(4))) unsigned u32x4;

#define MFMA32(a, b, c) __builtin_amdgcn_mfma_f32_32x32x16_bf16(a, b, c, 0, 0, 0)

constexpr int Bc = 8, Hc = 8;
constexpr int NQ = 1024;      // query rows per (b,h)
constexpr int NK = 1024;      // key rows per (b,h)
constexpr int RS = 512;       // H*E floats: row stride in f32 tensors
constexpr int Ec = 64;        // head dim
constexpr int KT = 128;       // keys per tile
constexpr int NT = NK / KT;   // 8 tiles
constexpr float QSCALE = 0.125f;  // 1/sqrt(64), exact pow2, folded into Q

__device__ __forceinline__ short f2bf(float x) {
    return (short)__builtin_bit_cast(unsigned short, __float2bfloat16(x));
}

__device__ __forceinline__ bf16x8 pack2(float4 a, float4 b) {
    bf16x8 r;
    r[0] = f2bf(a.x); r[1] = f2bf(a.y); r[2] = f2bf(a.z); r[3] = f2bf(a.w);
    r[4] = f2bf(b.x); r[5] = f2bf(b.y); r[6] = f2bf(b.z); r[7] = f2bf(b.w);
    return r;
}

__device__ __forceinline__ bf16x8 pack2s(float4 a, float4 b, float s) {
    bf16x8 r;
    r[0] = f2bf(a.x * s); r[1] = f2bf(a.y * s); r[2] = f2bf(a.z * s); r[3] = f2bf(a.w * s);
    r[4] = f2bf(b.x * s); r[5] = f2bf(b.y * s); r[6] = f2bf(b.z * s); r[7] = f2bf(b.w * s);
    return r;
}

__device__ __forceinline__ unsigned cvtpk(float a, float b) {
    // compiler fuses to v_cvt_pk_bf16_f32 (m240: don't hand-write the asm)
    unsigned lo = (unsigned short)__builtin_bit_cast(unsigned short, __float2bfloat16(a));
    unsigned hi = (unsigned short)__builtin_bit_cast(unsigned short, __float2bfloat16(b));
    return lo | (hi << 16);
}

__device__ __forceinline__ void gload16(const short* src, short* dst) {
    // direct global->LDS DMA, 16B/lane; LDS dest = wave-uniform base + lane*16
    __builtin_amdgcn_global_load_lds((const __attribute__((address_space(1))) void*)src,
                                     (__attribute__((address_space(3))) void*)dst, 16, 0, 0);
}

// ---------------- pass 1: K/V fp32 -> bf16, V transposed ----------------
// Kbf: [head(64)][key(1024)][e(64)]   Vt: [head(64)][e(64)][key(1024)]
__global__ __launch_bounds__(256, 4)
void cvt_kv(const float* __restrict__ Kg, const float* __restrict__ Vg,
            short* __restrict__ Kbf, short* __restrict__ Vt) {
    __shared__ __attribute__((aligned(16))) short Vl[64][72];
    const int tid  = threadIdx.x;
    const int head = blockIdx.x >> 4;
    const int kb   = blockIdx.x & 15;
    const int b    = head >> 3, h = head & 7;
    const int row  = tid >> 2, q = tid & 3;

    const size_t gin = (((size_t)(b * NK + kb * 64 + row)) * 8 + h) * 64 + q * 16;
    const float4* kp = (const float4*)(Kg + gin);
    float4 k0 = kp[0], k1 = kp[1], k2 = kp[2], k3 = kp[3];
    short* kout = Kbf + ((size_t)head * NK + kb * 64 + row) * 64 + q * 16;
    ((bf16x8*)kout)[0] = pack2(k0, k1);
    ((bf16x8*)kout)[1] = pack2(k2, k3);

    const float4* vp = (const float4*)(Vg + gin);
    float4 v0 = vp[0], v1 = vp[1], v2 = vp[2], v3 = vp[3];
    const float vv[16] = {v0.x, v0.y, v0.z, v0.w, v1.x, v1.y, v1.z, v1.w,
                          v2.x, v2.y, v2.z, v2.w, v3.x, v3.y, v3.z, v3.w};
#pragma unroll
    for (int j = 0; j < 16; ++j) Vl[q * 16 + j][row] = f2bf(vv[j]);
    __syncthreads();
    short* vout = Vt + ((size_t)head * Ec + row) * NK + kb * 64 + q * 16;
    ((bf16x8*)vout)[0] = *(const bf16x8*)&Vl[row][q * 16];
    ((bf16x8*)vout)[1] = *(const bf16x8*)&Vl[row][q * 16 + 8];
}

// ---------------- pass 2: swapped-QK^T 32x32 flash attention ----------------
// S^T = mfma(A=K, B=Q): lane holds P^T[key][q=lane&31] in regs -> in-register
// softmax + cvt_pk/permlane32_swap relayout -> O^T = mfma(A=V^T, B=P^T).
// LDS tiles XOR-swizzled at 16B granularity: byte ^= (row&7)<<4, with the
// inverse swizzle applied to the global source of global_load_lds (rule 21).
__global__ __launch_bounds__(256, 2)
void fully_attn_kernel(const float* __restrict__ Qg, const short* __restrict__ Kbf,
                       const short* __restrict__ Vt, float* __restrict__ Og) {
    __shared__ __attribute__((aligned(16))) short Kl[2][KT][64];  // [key][e] 128B rows
    __shared__ __attribute__((aligned(16))) short Vl[2][64][KT];  // [e][key] 256B rows

    const int tid  = threadIdx.x;
    const int lane = tid & 63;
    const int wv   = tid >> 6;
    const int ql   = lane & 31;   // q column
    const int hi   = lane >> 5;   // k-half select
    const int swz  = (lane & 7) << 4;  // frag-read swizzle (row&7 == lane&7)

    // XCD-aware remap: one head's 8 blocks share an XCD (L2 keeps its 256KB K/V)
    const int bid  = blockIdx.x;
    const int head = (bid & 7) * 8 + (bid >> 6);
    const int qb   = (bid >> 3) & 7;
    const int b    = head >> 3, h = head & 7;

    const size_t headQ = (size_t)b * NQ * RS + (size_t)h * Ec;
    const short* KbfH = Kbf + (size_t)head * NK * Ec;
    const short* VtH  = Vt + (size_t)head * Ec * NK;

    // ---- Q as B-operand frags (col=q=lane&31, k=e=hi*8+i), scale folded ----
    const int qrow = qb * 128 + wv * 32 + ql;
    const float* qp = Qg + headQ + (size_t)qrow * RS;
    bf16x8 qf[4];
#pragma unroll
    for (int j = 0; j < 4; ++j) {
        const float4* q4 = (const float4*)(qp + j * 16 + hi * 8);
        qf[j] = pack2s(q4[0], q4[1], QSCALE);
    }

    // ---- staging geometry ----
    const int klocal = lane >> 3;          // K: 8 rows/call, chunk lane&7
    const int kj     = (lane & 7) ^ (klocal & 7);
    const int vlocal = lane >> 4;          // V: 4 rows/call, chunk lane&15

#define STAGE(buf, tt)                                                            \
    {                                                                             \
        _Pragma("unroll")                                                         \
        for (int s = 0; s < 4; ++s)                                               \
            gload16(KbfH + (size_t)((tt) * KT + wv * 32 + s * 8 + klocal) * 64 +  \
                        kj * 8,                                                   \
                    &Kl[buf][wv * 32 + s * 8][0]);                                \
        _Pragma("unroll")                                                         \
        for (int s = 0; s < 4; ++s)                                               \
            gload16(VtH + (size_t)(wv * 16 + s * 4 + vlocal) * NK + (tt) * KT +   \
                        (((lane & 15) ^ ((s * 4 + vlocal) & 7)) * 8),             \
                    &Vl[buf][wv * 16 + s * 4][0]);                                \
    }

    STAGE(0, 0);
    __syncthreads();

    float m_r = -1e30f, l_r = 0.0f;
    f32x16 o0 = (f32x16)(0.0f), o1 = (f32x16)(0.0f);

    int cur = 0;
    for (int t = 0; t < NT; ++t) {
        if (t + 1 < NT) STAGE(cur ^ 1, t + 1);  // prefetch flies under compute

        // ---- S^T: p[kt][reg] = S[key = kt*32+(reg&3)+8*(reg>>2)+4*hi][q=ql] ----
        f32x16 p[4];
        __builtin_amdgcn_s_setprio(1);
#pragma unroll
        for (int kt = 0; kt < 4; ++kt) {
            const char* kr = (const char*)&Kl[cur][kt * 32 + ql][0];
            f32x16 acc = (f32x16)(0.0f);
#pragma unroll
            for (int j = 0; j < 4; ++j) {
                bf16x8 kf = *(const bf16x8*)(kr + ((j * 32 + hi * 16) ^ swz));
                acc = MFMA32(kf, qf[j], acc);
            }
            p[kt] = acc;
        }
        __builtin_amdgcn_s_setprio(0);

        // ---- in-register online softmax (lane + lane^32 partner share row q) ----
        float pm = -1e30f;
#pragma unroll
        for (int kt = 0; kt < 4; ++kt)
#pragma unroll
            for (int i = 0; i < 16; ++i) pm = fmaxf(pm, p[kt][i]);
        pm = fmaxf(pm, __shfl_xor(pm, 32));
        const float mn = fmaxf(m_r, pm);
        const float alpha = __expf(m_r - mn);
        float rs = 0.0f;
#pragma unroll
        for (int kt = 0; kt < 4; ++kt)
#pragma unroll
            for (int i = 0; i < 16; ++i) {
                float e = __expf(p[kt][i] - mn);
                p[kt][i] = e;
                rs += e;
            }
        rs += __shfl_xor(rs, 32);
        l_r = l_r * alpha + rs;
        m_r = mn;
#pragma unroll
        for (int i = 0; i < 16; ++i) { o0[i] *= alpha; o1[i] *= alpha; }

        // ---- PV: per 16-key chunk m, build P B-frag in-register, 2 MFMAs ----
        __builtin_amdgcn_s_setprio(1);
#pragma unroll
        for (int m = 0; m < 8; ++m) {
            const int kt = m >> 1, r0 = (m & 1) * 8;
            unsigned a0 = cvtpk(p[kt][r0 + 0], p[kt][r0 + 1]);
            unsigned a1 = cvtpk(p[kt][r0 + 2], p[kt][r0 + 3]);
            unsigned b0 = cvtpk(p[kt][r0 + 4], p[kt][r0 + 5]);
            unsigned b1 = cvtpk(p[kt][r0 + 6], p[kt][r0 + 7]);
            asm("v_permlane32_swap_b32 %0, %1" : "+v"(a0), "+v"(b0));
            asm("v_permlane32_swap_b32 %0, %1" : "+v"(a1), "+v"(b1));
            u32x4 w = {a0, a1, b0, b1};
            bf16x8 pf = __builtin_bit_cast(bf16x8, w);
            const int cb = (m * 32 + hi * 16) ^ swz;
            bf16x8 v0 = *(const bf16x8*)((const char*)&Vl[cur][ql][0] + cb);
            bf16x8 v1 = *(const bf16x8*)((const char*)&Vl[cur][32 + ql][0] + cb);
            o0 = MFMA32(v0, pf, o0);
            o1 = MFMA32(v1, pf, o1);
        }
        __builtin_amdgcn_s_setprio(0);

        __syncthreads();  // drains vmcnt: prefetched tile landed
        cur ^= 1;
    }

    // ---- epilogue: O^T regs -> O[q][e] ----
    const float inv = 1.0f / l_r;
    float* op = Og + headQ + (size_t)qrow * RS;
#pragma unroll
    for (int i = 0; i < 16; ++i) {
        const int e = (i & 3) + 8 * (i >> 2) + 4 * hi;
        op[e]      = o0[i] * inv;
        op[32 + e] = o1[i] * inv;
    }
}

extern "C" void kernel_launch(void* const* d_in, const int* in_sizes, int n_in,
                              void* d_out, int out_size, void* d_ws, size_t ws_size,
                              hipStream_t stream) {
    const float* Qg = (const float*)d_in[0];
    const float* Kg = (const float*)d_in[1];
    const float* Vg = (const float*)d_in[2];
    float* Og = (float*)d_out;

    short* Kbf = (short*)d_ws;                         // 8.39 MB
    short* Vt  = (short*)d_ws + (size_t)64 * NK * Ec;  // 8.39 MB

    hipLaunchKernelGGL(cvt_kv, dim3(64 * 16), dim3(256), 0, stream, Kg, Vg, Kbf, Vt);
    hipLaunchKernelGGL(fully_attn_kernel, dim3(512), dim3(256), 0, stream,
                       Qg, Kbf, Vt, Og);
}